// Round 1
// baseline (3174.495 us; speedup 1.0000x reference)
//
#include <hip/hip_runtime.h>

#define NS   50000
#define LSEQ 32
#define IND  64
#define HIDN 64
#define OUTD 128
#define NR   11
#define M1   16
#define M2   32

__device__ __forceinline__ float fsigmoid(float x) {
  return __fdividef(1.f, 1.f + __expf(-x));
}
__device__ __forceinline__ float ftanh_(float x) {
  return 1.f - __fdividef(2.f, __expf(2.f * x) + 1.f);
}

// ---------------------------------------------------------------------------
// K1: fused gather + LSTM + relation-masked pooling.
// WG = 256 threads, 16 samples. Thread j owns z-column j (W rows in VGPRs).
// ---------------------------------------------------------------------------
__global__ __launch_bounds__(256, 2) void lstm_pool_kernel(
    const int* __restrict__ nbr, const int* __restrict__ lens,
    const int* __restrict__ rels, const float* __restrict__ adjw,
    const float* __restrict__ feat, const float* __restrict__ Wih,
    const float* __restrict__ Whh, float* __restrict__ pooled_g,
    int s0, int cnt)
{
  __shared__ __align__(16) float xs[M1][IND];       // 4 KB, x_t tile
  __shared__ __align__(16) float hs[M1][HIDN];      // 4 KB, h tile
  __shared__ __align__(16) float zb[M1][4 * HIDN];  // 16 KB, z scratch
  __shared__ int   sh_nbr[M1][LSEQ];
  __shared__ int   sh_rel[M1][LSEQ];
  __shared__ float sh_w[M1][LSEQ];
  __shared__ int   sh_len[M1];

  const int tid = threadIdx.x;
  const int wg0 = s0 + blockIdx.x * M1;

  // stage per-sample metadata (coalesced, once)
  for (int i = tid; i < M1 * LSEQ; i += 256) {
    int s = i >> 5, l = i & 31;
    int gs = wg0 + s;
    bool ok = (gs - s0) < cnt;
    sh_nbr[s][l] = ok ? nbr[(size_t)gs * LSEQ + l] : 0;
    sh_rel[s][l] = ok ? rels[(size_t)gs * LSEQ + l] : 0;
    sh_w[s][l]   = ok ? adjw[(size_t)gs * LSEQ + l] : 0.f;
  }
  if (tid < M1) {
    int gs = wg0 + tid;
    sh_len[tid] = ((gs - s0) < cnt) ? lens[gs] : 0;
  }
  for (int i = tid; i < M1 * HIDN; i += 256) ((float*)hs)[i] = 0.f;

  // W_ih row tid + W_hh row tid -> 128 VGPRs (stays for all 32 steps)
  float4 wih[16], whh[16];
  {
    const float4* a = (const float4*)(Wih + tid * IND);
    const float4* b = (const float4*)(Whh + tid * IND);
#pragma unroll
    for (int k = 0; k < 16; ++k) { wih[k] = a[k]; whh[k] = b[k]; }
  }

  const int u = tid & 63, sg = tid >> 6;  // cell-update role: unit u, sample group sg
  float c[4] = {0.f, 0.f, 0.f, 0.f};
  float pooled[4][NR];
#pragma unroll
  for (int ss = 0; ss < 4; ++ss)
#pragma unroll
    for (int rr = 0; rr < NR; ++rr) pooled[ss][rr] = 0.f;

  __syncthreads();

#pragma unroll 1
  for (int t = 0; t < LSEQ; ++t) {
    // gather x_t (zero beyond length, matching the feat_ext zero row)
    {
      int s = tid >> 4, q = tid & 15;
      float4 v = make_float4(0.f, 0.f, 0.f, 0.f);
      if (t < sh_len[s]) {
        int nid = sh_nbr[s][t];
        v = *(const float4*)(feat + (size_t)nid * IND + (q << 2));
      }
      *(float4*)(&xs[s][q << 2]) = v;
    }
    __syncthreads();  // xs ready; hs from prev update ready; zb free

    // z-phase: thread j computes z[s][j] for all 16 samples.
    // LDS reads are wave-uniform broadcasts (conflict-free); weights in regs.
    float acc[M1];
#pragma unroll
    for (int s = 0; s < M1; ++s) acc[s] = 0.f;
#pragma unroll
    for (int k = 0; k < 16; ++k) {
      const float4 wi = wih[k], wh = whh[k];
#pragma unroll
      for (int s = 0; s < M1; ++s) {
        float4 xv = *(const float4*)(&xs[s][k << 2]);
        float4 hv = *(const float4*)(&hs[s][k << 2]);
        acc[s] += xv.x * wi.x + xv.y * wi.y + xv.z * wi.z + xv.w * wi.w
                + hv.x * wh.x + hv.y * wh.y + hv.z * wh.z + hv.w * wh.w;
      }
    }
#pragma unroll
    for (int s = 0; s < M1; ++s) zb[s][tid] = acc[s];
    __syncthreads();  // zb ready

    // update-phase: thread (u, sg) updates c,h for 4 samples; pool per relation.
#pragma unroll
    for (int ss = 0; ss < 4; ++ss) {
      int s = sg * 4 + ss;
      float zi = zb[s][u], zf = zb[s][u + 64];
      float zg = zb[s][u + 128], zo = zb[s][u + 192];
      float gi = fsigmoid(zi), gf = fsigmoid(zf);
      float gg = ftanh_(zg),   go = fsigmoid(zo);
      float cc = gf * c[ss] + gi * gg;
      c[ss] = cc;
      float h = go * ftanh_(cc);
      hs[s][u] = h;
      float wv = (t < sh_len[s]) ? sh_w[s][t] : 0.f;
      float wh_ = wv * h;
      int r = sh_rel[s][t];
      // static-indexed accumulator: 11 predicated FMAs (avoids scratch spill)
#pragma unroll
      for (int rr = 0; rr < NR; ++rr)
        pooled[ss][rr] += (rr == r) ? wh_ : 0.f;
    }
    // next iteration's gather-barrier separates hs write from next z-read
  }

  // write pooled [cnt][11][64], coalesced over u
#pragma unroll
  for (int ss = 0; ss < 4; ++ss) {
    int gs = wg0 + sg * 4 + ss;
    if ((gs - s0) < cnt) {
      size_t base = (size_t)(gs - s0) * (NR * HIDN);
#pragma unroll
      for (int rr = 0; rr < NR; ++rr)
        pooled_g[base + rr * HIDN + u] = pooled[ss][rr];
    }
  }
}

// ---------------------------------------------------------------------------
// K2: proj[s] = sum_r pooled[s][r] @ W_r, atomically scattered to out[nodes[s]].
// W_r staged in LDS; consecutive lanes read consecutive 16B (conflict-free).
// ---------------------------------------------------------------------------
__global__ __launch_bounds__(256, 2) void rgc_scatter_kernel(
    const float* __restrict__ pooled_g, const float* __restrict__ Wr,
    const int* __restrict__ nodes, float* __restrict__ out,
    int s0, int cnt)
{
  __shared__ __align__(16) float Wl[HIDN][OUTD];  // 32 KB
  __shared__ __align__(16) float pl[M2][HIDN];    // 8 KB
  const int tid = threadIdx.x;
  const int o4 = tid & 31, sg = tid >> 5;  // o-block 0..31, sample-group 0..7
  const int sbase = blockIdx.x * M2;

  float4 proj[4];
#pragma unroll
  for (int i = 0; i < 4; ++i) proj[i] = make_float4(0.f, 0.f, 0.f, 0.f);

  for (int r = 0; r < NR; ++r) {
    __syncthreads();
    for (int i = tid; i < HIDN * OUTD; i += 256)
      ((float*)Wl)[i] = Wr[r * HIDN * OUTD + i];
    for (int i = tid; i < M2 * HIDN; i += 256) {
      int s = i >> 6, uu = i & 63;
      int ls = sbase + s;
      pl[s][uu] = (ls < cnt) ? pooled_g[((size_t)ls * NR + r) * HIDN + uu] : 0.f;
    }
    __syncthreads();
#pragma unroll 4
    for (int uu = 0; uu < HIDN; ++uu) {
      float4 w4 = *(const float4*)(&Wl[uu][o4 << 2]);
#pragma unroll
      for (int ss = 0; ss < 4; ++ss) {
        float p = pl[sg * 4 + ss][uu];  // broadcast
        proj[ss].x += p * w4.x; proj[ss].y += p * w4.y;
        proj[ss].z += p * w4.z; proj[ss].w += p * w4.w;
      }
    }
  }

#pragma unroll
  for (int ss = 0; ss < 4; ++ss) {
    int ls = sbase + sg * 4 + ss;
    if (ls < cnt) {
      int nd = nodes[s0 + ls];
      float* dst = out + (size_t)nd * OUTD + (o4 << 2);
      atomicAdd(dst + 0, proj[ss].x);
      atomicAdd(dst + 1, proj[ss].y);
      atomicAdd(dst + 2, proj[ss].z);
      atomicAdd(dst + 3, proj[ss].w);
    }
  }
}

__global__ void relu_kernel(float4* __restrict__ out, int n4) {
  int i = blockIdx.x * 256 + threadIdx.x;
  if (i < n4) {
    float4 v = out[i];
    v.x = fmaxf(v.x, 0.f); v.y = fmaxf(v.y, 0.f);
    v.z = fmaxf(v.z, 0.f); v.w = fmaxf(v.w, 0.f);
    out[i] = v;
  }
}

extern "C" void kernel_launch(void* const* d_in, const int* in_sizes, int n_in,
                              void* d_out, int out_size, void* d_ws, size_t ws_size,
                              hipStream_t stream) {
  const int*   nbr   = (const int*)d_in[0];
  const int*   lens  = (const int*)d_in[1];
  const int*   rels  = (const int*)d_in[2];
  const int*   nodes = (const int*)d_in[3];
  const float* adjw  = (const float*)d_in[4];
  const float* feat  = (const float*)d_in[5];
  const float* Wih   = (const float*)d_in[6];
  const float* Whh   = (const float*)d_in[7];
  const float* Wr    = (const float*)d_in[8];
  float* out = (float*)d_out;

  hipMemsetAsync(d_out, 0, (size_t)NS * OUTD * sizeof(float), stream);

  // chunk size derived deterministically from ws_size (pooled = cnt*11*64 f32)
  size_t per = (size_t)NR * HIDN * sizeof(float);
  long long ch = (long long)(ws_size / per);
  if (ch > NS) ch = NS;
  ch &= ~31LL;
  if (ch < 32) ch = 32;

  for (int s0 = 0; s0 < NS; s0 += (int)ch) {
    int cnt = (NS - s0 < (int)ch) ? (NS - s0) : (int)ch;
    lstm_pool_kernel<<<(cnt + M1 - 1) / M1, 256, 0, stream>>>(
        nbr, lens, rels, adjw, feat, Wih, Whh, (float*)d_ws, s0, cnt);
    rgc_scatter_kernel<<<(cnt + M2 - 1) / M2, 256, 0, stream>>>(
        (const float*)d_ws, Wr, nodes, out, s0, cnt);
  }
  relu_kernel<<<(NS * OUTD / 4 + 255) / 256, 256, 0, stream>>>(
      (float4*)out, NS * OUTD / 4);
}

// Round 2
// 883.603 us; speedup vs baseline: 3.5927x; 3.5927x over previous
//
#include <hip/hip_runtime.h>

#define NS   50000
#define LSEQ 32
#define IND  64
#define HIDN 64
#define OUTD 128
#define NR   11
#define M2   32

using bf16x8  = __attribute__((ext_vector_type(8))) short;
using f32x16  = __attribute__((ext_vector_type(16))) float;
using short4v = __attribute__((ext_vector_type(4))) short;

__device__ __forceinline__ short f2bf(float f) {
  unsigned u = __float_as_uint(f);
  u = (u + 0x7FFFu + ((u >> 16) & 1u)) >> 16;  // RNE
  return (short)u;
}
__device__ __forceinline__ float fsigmoid(float x) {
  return __fdividef(1.f, 1.f + __expf(-x));
}
__device__ __forceinline__ float ftanh_(float x) {
  return 1.f - __fdividef(2.f, __expf(2.f * x) + 1.f);
}

// ---------------------------------------------------------------------------
// K1: fused gather + bf16-MFMA LSTM + relation pooling.
// WG = 512 thr (8 waves), 32 samples. Wave w owns z-rows [32w,32w+32) of the
// gate-permuted weight matrix W'[rr][k]: unit u = 8w + (rr>>2), gate = rr&3,
// k = [x(0..63) | h(64..127)]. A (weights) stationary in VGPRs; B (activations)
// streamed from swizzled LDS. C/D layout => gate update is lane-local.
// ---------------------------------------------------------------------------
__global__ __launch_bounds__(512, 3) void lstm_mfma_kernel(
    const int* __restrict__ nbr, const int* __restrict__ lens,
    const int* __restrict__ rels, const float* __restrict__ adjw,
    const float* __restrict__ feat, const float* __restrict__ Wih,
    const float* __restrict__ Whh, float* __restrict__ pooled_g,
    int s0, int cnt)
{
  __shared__ short xh[32 * 128];   // [32 samp][128 k] bf16, 256B row, XOR-swizzled
  __shared__ float sh_w[32][33];
  __shared__ int   sh_rel[32][33];
  __shared__ int   sh_nbr[32][33];
  __shared__ int   sh_len[32];

  const int tid   = threadIdx.x;
  const int lane  = tid & 63;
  const int w     = tid >> 6;
  const int sbase = blockIdx.x * 32;

  // stage per-sample metadata (coalesced)
  for (int i = tid; i < 32 * 32; i += 512) {
    int ss = i >> 5, l = i & 31;
    int gs = sbase + ss;
    bool ok = gs < cnt;
    size_t off = (size_t)(s0 + gs) * LSEQ + l;
    sh_nbr[ss][l] = ok ? nbr[off] : 0;
    sh_rel[ss][l] = ok ? rels[off] : 0;
    sh_w[ss][l]   = ok ? adjw[off] : 0.f;
  }
  if (tid < 32) sh_len[tid] = (sbase + tid < cnt) ? lens[s0 + sbase + tid] : 0;
  for (int i = tid; i < 32 * 128; i += 512) xh[i] = 0;  // h(0) = 0

  // ---- weights -> A fragments (bf16, stationary) ----
  bf16x8 Af[8];
  {
    const int r = lane & 31, kh = lane >> 5;
    const int gate = r & 3, u = w * 8 + (r >> 2);
    const int row = gate * 64 + u;  // row in [4H, *] gate order i,f,g,o
#pragma unroll
    for (int kc = 0; kc < 8; ++kc) {
      int k0 = kc * 16 + kh * 8;
      const float* src = (k0 < 64) ? (Wih + row * 64 + k0)
                                   : (Whh + row * 64 + (k0 - 64));
      float4 f0 = *(const float4*)(src);
      float4 f1 = *(const float4*)(src + 4);
      bf16x8 a;
      a[0] = f2bf(f0.x); a[1] = f2bf(f0.y); a[2] = f2bf(f0.z); a[3] = f2bf(f0.w);
      a[4] = f2bf(f1.x); a[5] = f2bf(f1.y); a[6] = f2bf(f1.z); a[7] = f2bf(f1.w);
      Af[kc] = a;
    }
  }

  const int s    = lane & 31;      // gate-phase sample
  const int hi   = lane >> 5;
  const int sxor = (s & 7) << 4;

  float c4[4] = {0.f, 0.f, 0.f, 0.f};
  float pooled[4][NR];
#pragma unroll
  for (int p = 0; p < 4; ++p)
#pragma unroll
    for (int r = 0; r < NR; ++r) pooled[p][r] = 0.f;

  const int gsamp = tid >> 4, gseg = tid & 15;  // gather roles
  const int gxor  = (gsamp & 7) << 4;

  __syncthreads();

  // prologue: gather x_0
  {
    float4 xv = make_float4(0.f, 0.f, 0.f, 0.f);
    if (0 < sh_len[gsamp]) {
      int nid = sh_nbr[gsamp][0];
      xv = *(const float4*)(feat + (size_t)nid * IND + gseg * 4);
    }
    short4v xb;
    xb[0] = f2bf(xv.x); xb[1] = f2bf(xv.y); xb[2] = f2bf(xv.z); xb[3] = f2bf(xv.w);
    int byte = gsamp * 256 + ((gseg * 8) ^ gxor);
    *(short4v*)(&xh[byte >> 1]) = xb;
  }
  __syncthreads();

#pragma unroll 1
  for (int t = 0; t < LSEQ; ++t) {
    // prefetch x_{t+1} (latency hides under MFMA + gates)
    float4 xn = make_float4(0.f, 0.f, 0.f, 0.f);
    const bool pf = (t + 1 < LSEQ);
    if (pf && (t + 1) < sh_len[gsamp]) {
      int nid = sh_nbr[gsamp][t + 1];
      xn = *(const float4*)(feat + (size_t)nid * IND + gseg * 4);
    }

    // z for this wave's 32 rows x 32 samples, K=128
    f32x16 acc = {};
#pragma unroll
    for (int kc = 0; kc < 8; ++kc) {
      int byte = s * 256 + (((kc * 32) + hi * 16) ^ sxor);
      bf16x8 b = *(const bf16x8*)(&xh[byte >> 1]);
      acc = __builtin_amdgcn_mfma_f32_32x32x16_bf16(Af[kc], b, acc, 0, 0, 0);
    }

    // lane-local gates: 4 units (u = 8w + 2p + hi) x 1 sample
    float h4[4];
    const int len_s = sh_len[s];
    float wv = (t < len_s) ? sh_w[s][t] : 0.f;
    int   rl = sh_rel[s][t];
#pragma unroll
    for (int p = 0; p < 4; ++p) {
      float zi = acc[4 * p + 0], zf = acc[4 * p + 1];
      float zg = acc[4 * p + 2], zo = acc[4 * p + 3];
      float gi = fsigmoid(zi), gf = fsigmoid(zf);
      float gg = ftanh_(zg),   go = fsigmoid(zo);
      float cc = gf * c4[p] + gi * gg;
      c4[p] = cc;
      float h = go * ftanh_(cc);
      h4[p] = h;
      float wh = wv * h;
#pragma unroll
      for (int r = 0; r < NR; ++r)
        pooled[p][r] += (r == rl) ? wh : 0.f;  // static-indexed accumulator
    }

    __syncthreads();  // all waves done reading xh(t)
#pragma unroll
    for (int p = 0; p < 4; ++p) {
      int u = w * 8 + 2 * p + hi;
      int byte = s * 256 + (((64 + u) * 2) ^ sxor);
      xh[byte >> 1] = f2bf(h4[p]);
    }
    if (pf) {
      short4v xb;
      xb[0] = f2bf(xn.x); xb[1] = f2bf(xn.y); xb[2] = f2bf(xn.z); xb[3] = f2bf(xn.w);
      int byte = gsamp * 256 + ((gseg * 8) ^ gxor);
      *(short4v*)(&xh[byte >> 1]) = xb;
    }
    __syncthreads();  // xh(t+1) ready
  }

  if (sbase + s < cnt) {
    size_t base = (size_t)(sbase + s) * (NR * HIDN);
#pragma unroll
    for (int p = 0; p < 4; ++p) {
      int u = w * 8 + 2 * p + hi;
#pragma unroll
      for (int r = 0; r < NR; ++r)
        pooled_g[base + r * HIDN + u] = pooled[p][r];
    }
  }
}

// ---------------------------------------------------------------------------
// K2: proj[s] = sum_r pooled[s][r] @ W_r, atomically scattered to out[nodes[s]].
// (unchanged, known-good)
// ---------------------------------------------------------------------------
__global__ __launch_bounds__(256, 2) void rgc_scatter_kernel(
    const float* __restrict__ pooled_g, const float* __restrict__ Wr,
    const int* __restrict__ nodes, float* __restrict__ out,
    int s0, int cnt)
{
  __shared__ __align__(16) float Wl[HIDN][OUTD];  // 32 KB
  __shared__ __align__(16) float pl[M2][HIDN];    // 8 KB
  const int tid = threadIdx.x;
  const int o4 = tid & 31, sg = tid >> 5;
  const int sbase = blockIdx.x * M2;

  float4 proj[4];
#pragma unroll
  for (int i = 0; i < 4; ++i) proj[i] = make_float4(0.f, 0.f, 0.f, 0.f);

  for (int r = 0; r < NR; ++r) {
    __syncthreads();
    for (int i = tid; i < HIDN * OUTD; i += 256)
      ((float*)Wl)[i] = Wr[r * HIDN * OUTD + i];
    for (int i = tid; i < M2 * HIDN; i += 256) {
      int ss = i >> 6, uu = i & 63;
      int ls = sbase + ss;
      pl[ss][uu] = (ls < cnt) ? pooled_g[((size_t)ls * NR + r) * HIDN + uu] : 0.f;
    }
    __syncthreads();
#pragma unroll 4
    for (int uu = 0; uu < HIDN; ++uu) {
      float4 w4 = *(const float4*)(&Wl[uu][o4 << 2]);
#pragma unroll
      for (int ss = 0; ss < 4; ++ss) {
        float p = pl[sg * 4 + ss][uu];
        proj[ss].x += p * w4.x; proj[ss].y += p * w4.y;
        proj[ss].z += p * w4.z; proj[ss].w += p * w4.w;
      }
    }
  }

#pragma unroll
  for (int ss = 0; ss < 4; ++ss) {
    int ls = sbase + sg * 4 + ss;
    if (ls < cnt) {
      int nd = nodes[s0 + ls];
      float* dst = out + (size_t)nd * OUTD + (o4 << 2);
      atomicAdd(dst + 0, proj[ss].x);
      atomicAdd(dst + 1, proj[ss].y);
      atomicAdd(dst + 2, proj[ss].z);
      atomicAdd(dst + 3, proj[ss].w);
    }
  }
}

__global__ void relu_kernel(float4* __restrict__ out, int n4) {
  int i = blockIdx.x * 256 + threadIdx.x;
  if (i < n4) {
    float4 v = out[i];
    v.x = fmaxf(v.x, 0.f); v.y = fmaxf(v.y, 0.f);
    v.z = fmaxf(v.z, 0.f); v.w = fmaxf(v.w, 0.f);
    out[i] = v;
  }
}

extern "C" void kernel_launch(void* const* d_in, const int* in_sizes, int n_in,
                              void* d_out, int out_size, void* d_ws, size_t ws_size,
                              hipStream_t stream) {
  const int*   nbr   = (const int*)d_in[0];
  const int*   lens  = (const int*)d_in[1];
  const int*   rels  = (const int*)d_in[2];
  const int*   nodes = (const int*)d_in[3];
  const float* adjw  = (const float*)d_in[4];
  const float* feat  = (const float*)d_in[5];
  const float* Wih   = (const float*)d_in[6];
  const float* Whh   = (const float*)d_in[7];
  const float* Wr    = (const float*)d_in[8];
  float* out = (float*)d_out;

  hipMemsetAsync(d_out, 0, (size_t)NS * OUTD * sizeof(float), stream);

  // chunk size from ws_size (pooled = cnt*11*64 f32)
  size_t per = (size_t)NR * HIDN * sizeof(float);
  long long ch = (long long)(ws_size / per);
  if (ch > NS) ch = NS;
  ch &= ~31LL;
  if (ch < 32) ch = 32;

  for (int s0 = 0; s0 < NS; s0 += (int)ch) {
    int cnt = (NS - s0 < (int)ch) ? (NS - s0) : (int)ch;
    lstm_mfma_kernel<<<(cnt + 31) / 32, 512, 0, stream>>>(
        nbr, lens, rels, adjw, feat, Wih, Whh, (float*)d_ws, s0, cnt);
    rgc_scatter_kernel<<<(cnt + M2 - 1) / M2, 256, 0, stream>>>(
        (const float*)d_ws, Wr, nodes, out, s0, cnt);
  }
  relu_kernel<<<(NS * OUTD / 4 + 255) / 256, 256, 0, stream>>>(
      (float4*)out, NS * OUTD / 4);
}

// Round 3
// 767.849 us; speedup vs baseline: 4.1343x; 1.1508x over previous
//
#include <hip/hip_runtime.h>

#define NS   50000
#define LSEQ 32
#define IND  64
#define HIDN 64
#define OUTD 128
#define NR   11

using bf16x8  = __attribute__((ext_vector_type(8))) short;
using f32x16  = __attribute__((ext_vector_type(16))) float;

union U8 { bf16x8 v; unsigned u[4]; uint2 d[2]; };

__device__ __forceinline__ unsigned cvt_pk_bf16(float a, float b) {
  unsigned r;
  asm volatile("v_cvt_pk_bf16_f32 %0, %1, %2" : "=v"(r) : "v"(a), "v"(b));
  return r;  // r[15:0] = bf16(a), r[31:16] = bf16(b)
}
__device__ __forceinline__ float fsig(float x) {
  return __fdividef(1.f, 1.f + __expf(-x));
}
__device__ __forceinline__ float ftanh_(float x) {
  return 1.f - __fdividef(2.f, __expf(2.f * x) + 1.f);
}
__device__ __forceinline__ void gload_lds16(const void* g, void* l) {
  __builtin_amdgcn_global_load_lds(
      (const __attribute__((address_space(1))) unsigned*)g,
      (__attribute__((address_space(3))) unsigned*)l, 16, 0, 0);
}

// ---------------------------------------------------------------------------
// K1: fused gather + bf16-MFMA LSTM + relation pooling (hi/lo bf16 output).
// 512 thr / 8 waves / 32 samples. Wave w owns 32 gate-permuted z-rows:
// row rr -> gate = rr&3, unit u = w*8 + 4*(q&1) + (q>>1), q = rr>>2, so each
// gate-phase lane owns 4 CONSECUTIVE units u0..u0+3 (single b64 h-write).
// Double-buffered swizzled activation tile -> ONE barrier per step.
// ---------------------------------------------------------------------------
__global__ __launch_bounds__(512, 4) void lstm_mfma_kernel(
    const int* __restrict__ nbr, const int* __restrict__ lens,
    const int* __restrict__ rels, const float* __restrict__ adjw,
    const float* __restrict__ feat, const float* __restrict__ Wih,
    const float* __restrict__ Whh,
    unsigned* __restrict__ phi, unsigned* __restrict__ plo,
    int s0, int cnt)
{
  __shared__ short xh[2 * 32 * 128];   // 2 x [32 samp][128 k] bf16, XOR-swizzled
  __shared__ int2  meta[32][33];       // {w bits, rel}
  __shared__ int   sh_nbr[32][33];
  __shared__ int   sh_len[32];

  const int tid   = threadIdx.x;
  const int lane  = tid & 63;
  const int w     = tid >> 6;
  const int sbase = blockIdx.x * 32;

  for (int i = tid; i < 32 * 32; i += 512) {
    int ss = i >> 5, l = i & 31;
    int gs = sbase + ss;
    bool ok = gs < cnt;
    size_t off = (size_t)(s0 + gs) * LSEQ + l;
    float wv = ok ? adjw[off] : 0.f;
    meta[ss][l] = make_int2(__float_as_int(wv), ok ? rels[off] : 0);
    sh_nbr[ss][l] = ok ? nbr[off] : 0;
  }
  if (tid < 32) sh_len[tid] = (sbase + tid < cnt) ? lens[s0 + sbase + tid] : 0;
  for (int i = tid; i < 2 * 32 * 128; i += 512) xh[i] = 0;

  // stationary A fragments (gate-permuted weight rows, bf16)
  bf16x8 Af[8];
  {
    const int rr = lane & 31, kh = lane >> 5;
    const int g = rr & 3, q = rr >> 2;
    const int u = w * 8 + 4 * (q & 1) + (q >> 1);
    const int row = g * 64 + u;
#pragma unroll
    for (int kc = 0; kc < 8; ++kc) {
      int k0 = kc * 16 + kh * 8;
      const float* src = (k0 < 64) ? (Wih + row * 64 + k0)
                                   : (Whh + row * 64 + (k0 - 64));
      float4 f0 = *(const float4*)(src);
      float4 f1 = *(const float4*)(src + 4);
      U8 a;
      a.u[0] = cvt_pk_bf16(f0.x, f0.y); a.u[1] = cvt_pk_bf16(f0.z, f0.w);
      a.u[2] = cvt_pk_bf16(f1.x, f1.y); a.u[3] = cvt_pk_bf16(f1.z, f1.w);
      Af[kc] = a.v;
    }
  }

  const int s    = lane & 31;          // gate-phase sample
  const int hi   = lane >> 5;
  const int sxor = (s & 15) << 4;
  const int u0   = w * 8 + 4 * hi;     // 4 consecutive units
  const int hoff = s * 128 + (((128 + u0 * 2) ^ sxor) >> 1);   // short idx
  const int gsamp = tid >> 4, gseg = tid & 15;                 // gather role
  const int goff  = gsamp * 128 + (((gseg * 8) ^ ((gsamp & 15) << 4)) >> 1);

  float c4[4] = {0.f, 0.f, 0.f, 0.f};
  float pooled[4][NR] = {};

  __syncthreads();
  const int len_s = sh_len[s];
  const int len_g = sh_len[gsamp];

  {  // prologue: x_0 -> buf0
    float4 xv = make_float4(0.f, 0.f, 0.f, 0.f);
    if (0 < len_g) {
      int nid = sh_nbr[gsamp][0];
      xv = *(const float4*)(feat + (size_t)nid * IND + gseg * 4);
    }
    *(uint2*)&xh[goff] = make_uint2(cvt_pk_bf16(xv.x, xv.y),
                                    cvt_pk_bf16(xv.z, xv.w));
  }
  __syncthreads();

#pragma unroll 2
  for (int t = 0; t < LSEQ; ++t) {
    const int bufR = (t & 1) * 4096;   // short units
    const int bufW = 4096 - bufR;

    // prefetch x_{t+1}
    float4 xn = make_float4(0.f, 0.f, 0.f, 0.f);
    if (t + 1 < len_g) {
      int nid = sh_nbr[gsamp][t + 1];
      xn = *(const float4*)(feat + (size_t)nid * IND + gseg * 4);
    }

    f32x16 acc = {};
#pragma unroll
    for (int kc = 0; kc < 8; ++kc) {
      int roff = s * 128 + (((kc * 32 + hi * 16) ^ sxor) >> 1);  // hoisted
      bf16x8 b = *(const bf16x8*)(&xh[bufR + roff]);
      acc = __builtin_amdgcn_mfma_f32_32x32x16_bf16(Af[kc], b, acc, 0, 0, 0);
    }

    int2 mt = meta[s][t];
    float wv = (t < len_s) ? __int_as_float(mt.x) : 0.f;
    int   rl = mt.y;

    float h4[4];
#pragma unroll
    for (int p = 0; p < 4; ++p) {
      float gi = fsig(acc[4 * p + 0]);
      float gf = fsig(acc[4 * p + 1]);
      float gg = ftanh_(acc[4 * p + 2]);
      float go = fsig(acc[4 * p + 3]);
      float cc = gf * c4[p] + gi * gg;
      c4[p] = cc;
      h4[p] = go * ftanh_(cc);
    }
#pragma unroll
    for (int r = 0; r < NR; ++r) {
      float mr = (rl == r) ? wv : 0.f;   // one select, 4 pure FMAs
      pooled[0][r] += mr * h4[0]; pooled[1][r] += mr * h4[1];
      pooled[2][r] += mr * h4[2]; pooled[3][r] += mr * h4[3];
    }

    *(uint2*)&xh[bufW + hoff] = make_uint2(cvt_pk_bf16(h4[0], h4[1]),
                                           cvt_pk_bf16(h4[2], h4[3]));
    *(uint2*)&xh[bufW + goff] = make_uint2(cvt_pk_bf16(xn.x, xn.y),
                                           cvt_pk_bf16(xn.z, xn.w));
    __syncthreads();   // single barrier: buf(t+1) complete
  }

  // pooled -> hi/lo bf16 planes: [samp][11][64] bf16 each (32 u32 per (s,r))
  if (sbase + s < cnt) {
    size_t base = ((size_t)(sbase + s) * NR) * 32;
#pragma unroll
    for (int r = 0; r < NR; ++r) {
      float p0 = pooled[0][r], p1 = pooled[1][r];
      float p2 = pooled[2][r], p3 = pooled[3][r];
      unsigned h0 = cvt_pk_bf16(p0, p1), h1 = cvt_pk_bf16(p2, p3);
      float l0 = p0 - __uint_as_float(h0 << 16);
      float l1 = p1 - __uint_as_float(h0 & 0xffff0000u);
      float l2 = p2 - __uint_as_float(h1 << 16);
      float l3 = p3 - __uint_as_float(h1 & 0xffff0000u);
      unsigned g0 = cvt_pk_bf16(l0, l1), g1 = cvt_pk_bf16(l2, l3);
      *(uint2*)&phi[base + r * 32 + (u0 >> 1)] = make_uint2(h0, h1);
      *(uint2*)&plo[base + r * 32 + (u0 >> 1)] = make_uint2(g0, g1);
    }
  }
}

// ---------------------------------------------------------------------------
// Prep: Wr[11][64][128] f32 -> wt[r]: [hi 16KB | lo 16KB], each [128 o][64 k]
// bf16 with baked 4-bit XOR swizzle (byte ^= (o&15)<<3) for conflict-free b64.
// ---------------------------------------------------------------------------
__global__ __launch_bounds__(256) void wprep_kernel(
    const float* __restrict__ Wr, unsigned* __restrict__ wt)
{
  __shared__ float wl[64 * 128];
  const int r = blockIdx.x;
  for (int i = threadIdx.x; i < 64 * 128; i += 256)
    wl[i] = Wr[r * 64 * 128 + i];
  __syncthreads();
  const int o = threadIdx.x >> 1, kb = (threadIdx.x & 1) * 32;
  const int sw = (o & 15) << 3;
  unsigned* hip = wt + r * 8192;
  unsigned* lop = hip + 4096;
  for (int k = kb; k < kb + 32; k += 2) {
    float f0 = wl[k * 128 + o], f1 = wl[(k + 1) * 128 + o];
    unsigned h = cvt_pk_bf16(f0, f1);
    float l0 = f0 - __uint_as_float(h << 16);
    float l1 = f1 - __uint_as_float(h & 0xffff0000u);
    unsigned l = cvt_pk_bf16(l0, l1);
    int byte = o * 128 + ((k * 2) ^ sw);
    hip[byte >> 2] = h;
    lop[byte >> 2] = l;
  }
}

// ---------------------------------------------------------------------------
// K2: proj = sum_r pooled_r @ W_r via split-bf16 MFMA (hi*hi + hi*lo + lo*hi),
// D[m=out][n=samp]; atomic scatter to out[nodes]. 256 thr / 4 waves / 64 samp.
// ---------------------------------------------------------------------------
__global__ __launch_bounds__(256, 4) void rgc_mfma_kernel(
    const unsigned* __restrict__ wt, const unsigned* __restrict__ phi,
    const unsigned* __restrict__ plo, const int* __restrict__ nodes,
    float* __restrict__ out, int s0, int cnt)
{
  __shared__ short wl[2 * 8192];   // 32KB: W hi | lo tile for current r
  const int tid = threadIdx.x, lane = tid & 63, nt = tid >> 6;
  const int l31 = lane & 31, lhi = lane >> 5;
  const int sbase = blockIdx.x * 64;

  const int row = nt * 32 + l31;            // wT row = out index
  const int rsw = (row & 15) << 3;
  int aoff[8];                               // short idx, [kc][half]
#pragma unroll
  for (int kc = 0; kc < 4; ++kc)
#pragma unroll
    for (int hf = 0; hf < 2; ++hf)
      aoff[kc * 2 + hf] = row * 64 + (((kc * 32 + lhi * 16 + hf * 8) ^ rsw) >> 1);

  f32x16 acc0 = {}, acc1 = {};

  for (int r = 0; r < NR; ++r) {
    __syncthreads();                 // previous tile's reads done
    {
      const char* src = (const char*)(wt + r * 8192);
#pragma unroll
      for (int i = 0; i < 8; ++i) {
        int off = (i * 4 + nt) * 1024 + lane * 16;
        gload_lds16(src + off, (char*)wl + off);
      }
    }
    __syncthreads();                 // staged (syncthreads drains vmcnt)

    bf16x8 ahi[4], alo[4];
#pragma unroll
    for (int kc = 0; kc < 4; ++kc) {
      U8 a, b;
      a.d[0] = *(const uint2*)&wl[aoff[kc * 2 + 0]];
      a.d[1] = *(const uint2*)&wl[aoff[kc * 2 + 1]];
      b.d[0] = *(const uint2*)&wl[8192 + aoff[kc * 2 + 0]];
      b.d[1] = *(const uint2*)&wl[8192 + aoff[kc * 2 + 1]];
      ahi[kc] = a.v; alo[kc] = b.v;
    }

#pragma unroll
    for (int st = 0; st < 2; ++st) {
      f32x16& accr = st ? acc1 : acc0;
      int samp = sbase + st * 32 + l31;
      size_t bb = ((size_t)samp * NR + r) * 32 + lhi * 4;
#pragma unroll
      for (int kc = 0; kc < 4; ++kc) {
        U8 bh, bl;
        *(uint4*)bh.u = *(const uint4*)&phi[bb + kc * 8];
        *(uint4*)bl.u = *(const uint4*)&plo[bb + kc * 8];
        accr = __builtin_amdgcn_mfma_f32_32x32x16_bf16(ahi[kc], bh.v, accr, 0, 0, 0);
        accr = __builtin_amdgcn_mfma_f32_32x32x16_bf16(ahi[kc], bl.v, accr, 0, 0, 0);
        accr = __builtin_amdgcn_mfma_f32_32x32x16_bf16(alo[kc], bh.v, accr, 0, 0, 0);
      }
    }
  }

#pragma unroll
  for (int st = 0; st < 2; ++st) {
    int sl = sbase + st * 32 + l31;
    if (sl < cnt) {
      int nd = nodes[s0 + sl];
      float* dst = out + (size_t)nd * OUTD + nt * 32;
      const f32x16& a = st ? acc1 : acc0;
#pragma unroll
      for (int j = 0; j < 16; ++j) {
        int m = (j & 3) + 8 * (j >> 2) + 4 * lhi;
        atomicAdd(dst + m, a[j]);
      }
    }
  }
}

__global__ void relu_kernel(float4* __restrict__ out, int n4) {
  int i = blockIdx.x * 256 + threadIdx.x;
  if (i < n4) {
    float4 v = out[i];
    v.x = fmaxf(v.x, 0.f); v.y = fmaxf(v.y, 0.f);
    v.z = fmaxf(v.z, 0.f); v.w = fmaxf(v.w, 0.f);
    out[i] = v;
  }
}

extern "C" void kernel_launch(void* const* d_in, const int* in_sizes, int n_in,
                              void* d_out, int out_size, void* d_ws, size_t ws_size,
                              hipStream_t stream) {
  const int*   nbr   = (const int*)d_in[0];
  const int*   lens  = (const int*)d_in[1];
  const int*   rels  = (const int*)d_in[2];
  const int*   nodes = (const int*)d_in[3];
  const float* adjw  = (const float*)d_in[4];
  const float* feat  = (const float*)d_in[5];
  const float* Wih   = (const float*)d_in[6];
  const float* Whh   = (const float*)d_in[7];
  const float* Wr    = (const float*)d_in[8];
  float* out = (float*)d_out;

  hipMemsetAsync(d_out, 0, (size_t)NS * OUTD * sizeof(float), stream);

  // ws layout: [0, 360448) swizzled W hi/lo; then pooled hi/lo bf16 planes.
  unsigned* wt = (unsigned*)d_ws;
  wprep_kernel<<<NR, 256, 0, stream>>>(Wr, wt);

  size_t avail = (ws_size > 360448) ? ws_size - 360448 : 0;
  long long cap = (long long)(avail / 2816);     // samples (1408B x 2 planes)
  long long ch = cap - 64;                        // 64-sample read slack
  ch &= ~63LL;
  if (ch > NS) ch = NS;
  if (ch < 64) ch = 64;
  unsigned* phi = (unsigned*)((char*)d_ws + 360448);
  unsigned* plo = phi + (size_t)cap * 352;        // 352 u32 = 1408B per sample

  for (int s0 = 0; s0 < NS; s0 += (int)ch) {
    int cnt = (NS - s0 < (int)ch) ? (NS - s0) : (int)ch;
    lstm_mfma_kernel<<<(cnt + 31) / 32, 512, 0, stream>>>(
        nbr, lens, rels, adjw, feat, Wih, Whh, phi, plo, s0, cnt);
    rgc_mfma_kernel<<<(cnt + 63) / 64, 256, 0, stream>>>(
        wt, phi, plo, nodes, out, s0, cnt);
  }
  relu_kernel<<<(NS * OUTD / 4 + 255) / 256, 256, 0, stream>>>(
      (float4*)out, NS * OUTD / 4);
}